// Round 5
// baseline (186.257 us; speedup 1.0000x reference)
//
#include <hip/hip_runtime.h>

// MyConv: masked 3x3 conv, B=8, Cin=Cout=128, H=W=128, pad=1, stride=1.
// v8: staging deleted. v5/v6/v7 all sat at 22-30% on EVERY pipe with 2
// barriers/round around LDS staging of data that FETCH=43MB proves is
// L2-resident (Common-mistake #7). v8 reads B-fragments DIRECTLY from
// global xp (linear layout now; lane(l16,q) frag(kw,j) at byte
// (nh*64+16j+l16+kw)*64 + q*16 -> contiguous 1KB/wave-instr, L2/L1-hot),
// A-fragments direct from wp as before. Zero main-loop barriers, zero LDS
// data traffic, zero global_load_lds: compiler free to pipeline loads
// across rounds with its own waitcnt counting; 4 waves/SIMD TLP hides L2
// latency. T1 XCD-swizzle (1024%8==0, bijective) keeps h-adjacent blocks
// (which share slab rows) on one XCD's L2.

typedef __bf16 bf16x8 __attribute__((ext_vector_type(8)));
typedef unsigned short u16x8 __attribute__((ext_vector_type(8)));
typedef float f32x4 __attribute__((ext_vector_type(4)));

__device__ __forceinline__ unsigned short f2bf(float f) {
    unsigned int u = __float_as_uint(f);
    u += 0x7fffu + ((u >> 16) & 1u);   // round-to-nearest-even
    return (unsigned short)(u >> 16);
}

// ---- merged setup: cvt x (blocks 0..4159) + pack W (blocks 4160..4735) ----
// xp now LINEAR: slab[(b*4+cb)*130+hh2], 130 w-rows x 32 ci bf16 (64B/row),
// chunk c of a row holds ci-group c (no swizzle -- no LDS banks to dodge).
__global__ void setup_all(const float* __restrict__ x, const float* __restrict__ wgt,
                          unsigned short* __restrict__ xp, unsigned short* __restrict__ wpp) {
    __shared__ float Lf[32 * 132];
    const int t   = threadIdx.x;
    const int bid = blockIdx.x;

    if (bid >= 4160) {   // ---- weight pack: wp[kh][cb][kw][m][ci32] ----
        const int e    = (bid - 4160) * 256 + t;
        const int j    = e & 31;
        const int m    = (e >> 5) & 127;
        const int r    = e >> 12;
        const int kw   = r - (r / 3) * 3;
        const int cbkh = r / 3;
        const int cb   = cbkh & 3;
        const int kh   = cbkh >> 2;
        wpp[e] = f2bf(wgt[((m * 128 + cb * 32 + j) * 3 + kh) * 3 + kw]);
        return;
    }

    // ---- x fp32 [b][ci][h][w] -> bf16 xp slab [(b*4+cb)*130+hh2][r=130][ci32] ----
    const int hh2 = bid % 130;
    const int cb  = (bid / 130) & 3;
    const int b   = bid / 520;
    u16x8* slab = (u16x8*)(xp + (size_t)(((b * 4 + cb) * 130 + hh2)) * 4160);
    const u16x8 z = {0, 0, 0, 0, 0, 0, 0, 0};

    if (hh2 == 0 || hh2 == 129) {      // guard slab
        for (int k = t; k < 520; k += 256) slab[k] = z;
        return;
    }
    const int h = hh2 - 1;

    #pragma unroll
    for (int u = 0; u < 4; ++u) {
        const int f  = t + 256 * u;    // 0..1023
        const int ci = f >> 5;
        const int w4 = f & 31;
        const float4 v = *(const float4*)(x + (((b * 128 + cb * 32 + ci) * 128 + h) << 7) + (w4 << 2));
        *(float4*)&Lf[ci * 132 + (w4 << 2)] = v;
    }
    __syncthreads();

    for (int k = t; k < 520; k += 256) {
        const int r = k >> 2;
        const int c = k & 3;
        u16x8 o;
        if (r == 0 || r == 129) {
            o = z;
        } else {
            const int w   = r - 1;
            const int ci0 = c << 3;            // LINEAR ci-group
            #pragma unroll
            for (int s = 0; s < 8; ++s) o[s] = f2bf(Lf[(ci0 + s) * 132 + w]);
        }
        slab[k] = o;
    }
}

__global__ __launch_bounds__(256, 4)
void myconv8(const unsigned short* __restrict__ xp,
             const int* __restrict__ mask,
             const unsigned short* __restrict__ wp,
             const float* __restrict__ bias,
             float* __restrict__ out)
{
    __shared__ float act[128];

    const int t = threadIdx.x;           // 0..255
    // T1 bijective XCD swizzle: grid 1024 = 8 XCDs x 128 logical blocks.
    const int swz = (blockIdx.x & 7) * 128 + (blockIdx.x >> 3);
    const int b = swz >> 7;
    const int h = swz & 127;

    const int lane = t & 63;
    const int l16  = lane & 15;
    const int q    = lane >> 4;
    const int g    = t >> 6;             // wave 0..3
    const int mh   = g & 1;              // Cout half (0:0..63, 1:64..127)
    const int nh   = g >> 1;             // w half    (0:0..63, 1:64..127)

    // ---- active map for row h (threads 0..127, t = w) ----
    if (t < 128) {
        int any = 0;
        #pragma unroll
        for (int kh = 0; kh < 3; ++kh) {
            int hh = h + kh - 1;
            if ((unsigned)hh < 128u) {
                const int* mrow = mask + (b * 128 + hh) * 128;
                #pragma unroll
                for (int kw = 0; kw < 3; ++kw) {
                    int ww = t + kw - 1;
                    if ((unsigned)ww < 128u) any |= mrow[ww];
                }
            }
        }
        act[t] = any ? 1.0f : 0.0f;
    }
    __syncthreads();   // the ONLY block-wide barrier

    // per-lane base byte offsets
    const unsigned char* xpB = (const unsigned char*)xp;
    const int boff = (nh * 64 + l16) * 64 + q * 16;          // + kw*64 + j*1024
    const unsigned char* agl = (const unsigned char*)wp + (mh * 64 + l16) * 64 + q * 16;

    f32x4 acc[4][4];
    const f32x4 fzero = {0.f, 0.f, 0.f, 0.f};
    #pragma unroll
    for (int i = 0; i < 4; ++i)
        #pragma unroll
        for (int j = 0; j < 4; ++j)
            acc[i][j] = fzero;

    for (int r = 0; r < 12; ++r) {       // r = kh*4 + cb
        const int cb = r & 3;
        const int kh = r >> 2;
        // slab for (b, cb, padded row h+kh); rows rr = w+kw within it
        const unsigned char* xb = xpB + (size_t)((b * 4 + cb) * 130 + h + kh) * 8320 + boff;
        const unsigned char* ar = agl + r * 24576;

        #pragma unroll
        for (int kw = 0; kw < 3; ++kw) {
            bf16x8 af[4];
            #pragma unroll
            for (int i = 0; i < 4; ++i)
                af[i] = *(const bf16x8*)(ar + kw * 8192 + i * 1024);
            bf16x8 bfr[4];
            #pragma unroll
            for (int j = 0; j < 4; ++j)
                bfr[j] = *(const bf16x8*)(xb + kw * 64 + j * 1024);
            #pragma unroll
            for (int i = 0; i < 4; ++i)
                #pragma unroll
                for (int j = 0; j < 4; ++j)
                    acc[i][j] = __builtin_amdgcn_mfma_f32_16x16x32_bf16(af[i], bfr[j], acc[i][j], 0, 0, 0);
        }
    }

    // ---- epilogue: (acc + bias) * active ----
    #pragma unroll
    for (int i = 0; i < 4; ++i) {
        const int m0 = mh * 64 + (i << 4) + (q << 2);
        const f32x4 bv = *(const f32x4*)(bias + m0);
        #pragma unroll
        for (int j = 0; j < 4; ++j) {
            const int w = nh * 64 + (j << 4) + l16;
            const float a = act[w];
            float* base = out + (((b << 7) + m0) << 14) + (h << 7) + w;
            #pragma unroll
            for (int rg = 0; rg < 4; ++rg)
                base[rg << 14] = (acc[i][j][rg] + bv[rg]) * a;
        }
    }
}

// ---------------- Round-1 fallback (used only if ws too small) ----------------
#define LDAF 40
__global__ __launch_bounds__(256, 2)
void myconv_fb(const float* __restrict__ x,
               const int* __restrict__ mask,
               const float* __restrict__ wgt,
               const float* __restrict__ bias,
               float* __restrict__ out)
{
    __shared__ unsigned short As[128 * LDAF];
    __shared__ unsigned short Bs[128 * LDAF];
    __shared__ float act[128];

    const int t   = threadIdx.x;
    const int blk = blockIdx.x;
    const int b   = blk >> 7;
    const int h   = blk & 127;

    if (t < 128) {
        int any = 0;
        #pragma unroll
        for (int kh = 0; kh < 3; ++kh) {
            int hh = h + kh - 1;
            if ((unsigned)hh < 128u) {
                const int* mrow = mask + (b * 128 + hh) * 128;
                #pragma unroll
                for (int kw = 0; kw < 3; ++kw) {
                    int ww = t + kw - 1;
                    if ((unsigned)ww < 128u) any |= mrow[ww];
                }
            }
        }
        act[t] = any ? 1.0f : 0.0f;
    }

    const int lane = t & 63;
    const int l16  = lane & 15;
    const int half = lane >> 4;
    const int wv   = t >> 6;
    const int wm   = (wv >> 1) << 6;
    const int wn   = (wv & 1) << 6;

    f32x4 acc[4][4];
    const f32x4 fzero = {0.f, 0.f, 0.f, 0.f};
    #pragma unroll
    for (int i = 0; i < 4; ++i)
        #pragma unroll
        for (int j = 0; j < 4; ++j)
            acc[i][j] = fzero;

    const int am  = t >> 3;
    const int ac4 = (t & 7) << 2;
    const int n     = t & 127;
    const int khalf = __builtin_amdgcn_readfirstlane(t >> 7);
    const int xb    = b << 21;

    for (int kt = 0; kt < 36; ++kt) {
        __syncthreads();
        #pragma unroll
        for (int jj = 0; jj < 4; ++jj) {
            const int m = am + (jj << 5);
            const float4 v = *(const float4*)(wgt + m * 1152 + kt * 32 + ac4);
            unsigned short* dst = &As[m * LDAF + ac4];
            dst[0] = f2bf(v.x); dst[1] = f2bf(v.y); dst[2] = f2bf(v.z); dst[3] = f2bf(v.w);
        }
        u16x8 bv0, bv1;
        #pragma unroll
        for (int s = 0; s < 16; ++s) {
            const int k  = kt * 32 + khalf * 16 + s;
            const int ci = (k * 7282) >> 16;
            const int r  = k - ci * 9;
            const int kh = (r >= 3) + (r >= 6);
            const int kw = r - kh * 3;
            const int hh = h + kh - 1;
            float v = 0.f;
            if ((unsigned)hh < 128u) {
                const int ww = n + kw - 1;
                if ((unsigned)ww < 128u)
                    v = x[xb + (ci << 14) + (hh << 7) + ww];
            }
            if (s < 8) bv0[s] = f2bf(v); else bv1[s - 8] = f2bf(v);
        }
        *(u16x8*)&Bs[n * LDAF + khalf * 16]     = bv0;
        *(u16x8*)&Bs[n * LDAF + khalf * 16 + 8] = bv1;

        __syncthreads();

        bf16x8 af[4], bfr[4];
        #pragma unroll
        for (int i = 0; i < 4; ++i)
            af[i] = *(const bf16x8*)&As[(wm + (i << 4) + l16) * LDAF + (half << 3)];
        #pragma unroll
        for (int j = 0; j < 4; ++j)
            bfr[j] = *(const bf16x8*)&Bs[(wn + (j << 4) + l16) * LDAF + (half << 3)];
        #pragma unroll
        for (int i = 0; i < 4; ++i)
            #pragma unroll
            for (int j = 0; j < 4; ++j)
                acc[i][j] = __builtin_amdgcn_mfma_f32_16x16x32_bf16(af[i], bfr[j], acc[i][j], 0, 0, 0);
    }

    #pragma unroll
    for (int i = 0; i < 4; ++i) {
        #pragma unroll
        for (int j = 0; j < 4; ++j) {
            const int ncol = wn + (j << 4) + l16;
            const float a  = act[ncol];
            #pragma unroll
            for (int rg = 0; rg < 4; ++rg) {
                const int m = wm + (i << 4) + (half << 2) + rg;
                out[(((b << 7) + m) << 14) + (h << 7) + ncol] =
                    (acc[i][j][rg] + bias[m]) * a;
            }
        }
    }
}

extern "C" void kernel_launch(void* const* d_in, const int* in_sizes, int n_in,
                              void* d_out, int out_size, void* d_ws, size_t ws_size,
                              hipStream_t stream) {
    const float* x    = (const float*)d_in[0];
    const int*   mask = (const int*)d_in[1];
    const float* wgt  = (const float*)d_in[2];
    const float* bias = (const float*)d_in[3];
    float* out        = (float*)d_out;

    const size_t XP_ELEMS = 4160ull * 4160;   // 17,305,600 bf16 (8*4*130 slabs)
    const size_t WP_ELEMS = 36ull * 128 * 32; //    147,456 bf16
    const size_t need = (XP_ELEMS + WP_ELEMS) * 2;

    if (ws_size >= need) {
        unsigned short* xpw = (unsigned short*)d_ws;
        unsigned short* wpw = xpw + XP_ELEMS;
        setup_all<<<dim3(4736), dim3(256), 0, stream>>>(x, wgt, xpw, wpw);
        myconv8<<<dim3(1024), dim3(256), 0, stream>>>(xpw, mask, wpw, bias, out);
    } else {
        myconv_fb<<<dim3(1024), dim3(256), 0, stream>>>(x, mask, wgt, bias, out);
    }
}

// Round 6
// 152.695 us; speedup vs baseline: 1.2198x; 1.2198x over previous
//
#include <hip/hip_runtime.h>

// MyConv: masked 3x3 conv, B=8, Cin=Cout=128, H=W=128, pad=1, stride=1.
// v9 = v5 conv (verbatim revert; 49.7us, best measured — v6 occupancy push
// 57.6, v7 counted-vmcnt 64.6, v8 no-LDS 83.6 all regressed) + setup_all
// bank-conflict fix. setup read Lf[(ci0+s)*132+w] had the 4 lanes sharing
// (w,s) differing only in ci bits 3-4 and 132*8==0 mod 32 -> structural
// 4-way LDS conflict on all 16 reads/thread. Fix: permute k-slot contents
// (slot (c,s) now holds ci=4s+c instead of 8c+s; MFMA only needs A,B to
// AGREE on k-slot->ci) -> read addr (4s+lc)*132+w: lanes' lc in {0..3}
// give banks 16s+4*lc+w -> distinct -> conflict-free, static indexing.
// wp pack applies the same permutation (ci = 4*(j&7)+(j>>3)); conv kernel
// untouched (agnostic to ci identity).

typedef __bf16 bf16x8 __attribute__((ext_vector_type(8)));
typedef unsigned short u16x8 __attribute__((ext_vector_type(8)));
typedef float f32x4 __attribute__((ext_vector_type(4)));

__device__ __forceinline__ unsigned short f2bf(float f) {
    unsigned int u = __float_as_uint(f);
    u += 0x7fffu + ((u >> 16) & 1u);   // round-to-nearest-even
    return (unsigned short)(u >> 16);
}

// ---- merged setup: cvt x (blocks 0..4159) + pack W (blocks 4160..4735) ----
__global__ void setup_all(const float* __restrict__ x, const float* __restrict__ wgt,
                          unsigned short* __restrict__ xp, unsigned short* __restrict__ wpp) {
    __shared__ float Lf[32 * 132];
    const int t   = threadIdx.x;
    const int bid = blockIdx.x;

    if (bid >= 4160) {   // ---- weight pack: wp[kh][cb][kw][m][ci32] ----
        const int e    = (bid - 4160) * 256 + t;
        const int j    = e & 31;               // k-slot within cb
        const int m    = (e >> 5) & 127;
        const int r    = e >> 12;
        const int kw   = r - (r / 3) * 3;
        const int cbkh = r / 3;
        const int cb   = cbkh & 3;
        const int kh   = cbkh >> 2;
        const int ci   = 4 * (j & 7) + (j >> 3);   // k-slot permutation (matches xp)
        wpp[e] = f2bf(wgt[((m * 128 + cb * 32 + ci) * 3 + kh) * 3 + kw]);
        return;
    }

    // ---- x fp32 [b][ci][h][w] -> bf16 xp slab [(b*4+cb)*130+hh2][r=130][ci32] ----
    const int hh2 = bid % 130;
    const int cb  = (bid / 130) & 3;
    const int b   = bid / 520;
    u16x8* slab = (u16x8*)(xp + (size_t)(((b * 4 + cb) * 130 + hh2)) * 4160);
    const u16x8 z = {0, 0, 0, 0, 0, 0, 0, 0};

    if (hh2 == 0 || hh2 == 129) {      // guard slab
        for (int k = t; k < 520; k += 256) slab[k] = z;
        return;
    }
    const int h = hh2 - 1;

    #pragma unroll
    for (int u = 0; u < 4; ++u) {
        const int f  = t + 256 * u;    // 0..1023
        const int ci = f >> 5;
        const int w4 = f & 31;
        const float4 v = *(const float4*)(x + (((b * 128 + cb * 32 + ci) * 128 + h) << 7) + (w4 << 2));
        *(float4*)&Lf[ci * 132 + (w4 << 2)] = v;
    }
    __syncthreads();

    for (int k = t; k < 520; k += 256) {
        const int r = k >> 2;
        const int c = k & 3;
        u16x8 o;
        if (r == 0 || r == 129) {
            o = z;
        } else {
            const int w  = r - 1;
            const int lc = c ^ ((r + (r >> 2)) & 3);   // swizzled logical chunk
            // slot (lc,s) holds ci = 4s+lc: lanes sharing (w,s) have distinct
            // lc -> banks (16s + 4*lc + w) mod 32 distinct -> conflict-free
            #pragma unroll
            for (int s = 0; s < 8; ++s) o[s] = f2bf(Lf[(4 * s + lc) * 132 + w]);
        }
        slab[k] = o;
    }
}

__device__ __forceinline__ void stage_slabs(const unsigned char* gx, unsigned char* ls, int t) {
    const int g    = t >> 6;       // wave-uniform
    const int lane = t & 63;
    #pragma unroll
    for (int u = 0; u < 8; ++u)
        __builtin_amdgcn_global_load_lds(
            (const __attribute__((address_space(1))) unsigned int*)(gx + u * 2048 + g * 1024 + lane * 16),
            (__attribute__((address_space(3))) unsigned int*)(ls + u * 2048 + g * 1024),
            16, 0, 0);
    if (t < 16)   // 256B tail, lanes 0-15 of wave 0
        __builtin_amdgcn_global_load_lds(
            (const __attribute__((address_space(1))) unsigned int*)(gx + 16384 + t * 16),
            (__attribute__((address_space(3))) unsigned int*)(ls + 16384),
            16, 0, 0);
}

__global__ __launch_bounds__(128, 2)
void myconv5(const unsigned short* __restrict__ xp,
             const int* __restrict__ mask,
             const unsigned short* __restrict__ wp,
             const float* __restrict__ bias,
             float* __restrict__ out)
{
    __shared__ __align__(16) unsigned char Xs[2][16640];  // dbuf: 2 slabs each
    __shared__ float act[256];

    const int t     = threadIdx.x;       // 0..127
    const int b     = blockIdx.x >> 7;
    const int mhalf = (blockIdx.x >> 6) & 1;
    const int h0    = (blockIdx.x & 63) << 1;

    const int lane = t & 63;
    const int l16  = lane & 15;
    const int q    = lane >> 4;
    const int g    = t >> 6;             // wave -> h row

    const unsigned char* xpB = (const unsigned char*)xp;

    // ---- stage round 0 immediately ----
    stage_slabs(xpB + (size_t)((b * 4 + 0) * 130 + h0 + 0) * 8320, &Xs[0][0], t);

    // ---- active map for rows h0, h0+1 (t = w) ----
    #pragma unroll
    for (int gg = 0; gg < 2; ++gg) {
        const int h = h0 + gg;
        int any = 0;
        #pragma unroll
        for (int kh = 0; kh < 3; ++kh) {
            int hh = h + kh - 1;
            if ((unsigned)hh < 128u) {
                const int* mrow = mask + (b * 128 + hh) * 128;
                #pragma unroll
                for (int kw = 0; kw < 3; ++kw) {
                    int ww = t + kw - 1;
                    if ((unsigned)ww < 128u) any |= mrow[ww];
                }
            }
        }
        act[gg * 128 + t] = any ? 1.0f : 0.0f;
    }

    // B fragment byte offsets (per kw, j-independent swizzle)
    int bb[3];
    #pragma unroll
    for (int kw = 0; kw < 3; ++kw) {
        const int rr   = l16 + kw;
        const int slot = q ^ ((rr + (rr >> 2)) & 3);
        bb[kw] = g * 8320 + rr * 64 + (slot << 4);
    }

    const unsigned char* agl = (const unsigned char*)wp + (mhalf * 64 + l16) * 64 + q * 16;

    f32x4 acc[4][8];
    const f32x4 fzero = {0.f, 0.f, 0.f, 0.f};
    #pragma unroll
    for (int i = 0; i < 4; ++i)
        #pragma unroll
        for (int j = 0; j < 8; ++j)
            acc[i][j] = fzero;

    __syncthreads();   // round-0 staging + act complete

    for (int r = 0; r < 12; ++r) {
        // ---- prefetch round r+1 into the other buffer (no wait here) ----
        if (r < 11) {
            const int rn = r + 1;
            stage_slabs(xpB + (size_t)((b * 4 + (rn & 3)) * 130 + h0 + (rn >> 2)) * 8320,
                        &Xs[(rn & 1)][0], t);
        }

        const unsigned char* ar = agl + r * 24576;
        const unsigned char* xb = &Xs[r & 1][0];
        #pragma unroll
        for (int kw = 0; kw < 3; ++kw) {
            bf16x8 af[4];
            #pragma unroll
            for (int i = 0; i < 4; ++i)
                af[i] = *(const bf16x8*)(ar + kw * 8192 + i * 1024);
            bf16x8 bfr[8];
            #pragma unroll
            for (int j = 0; j < 8; ++j)
                bfr[j] = *(const bf16x8*)(xb + bb[kw] + j * 1024);
            #pragma unroll
            for (int i = 0; i < 4; ++i)
                #pragma unroll
                for (int j = 0; j < 8; ++j)
                    acc[i][j] = __builtin_amdgcn_mfma_f32_16x16x32_bf16(af[i], bfr[j], acc[i][j], 0, 0, 0);
        }

        __syncthreads();   // drains r+1 staging (overlapped with compute above)
    }

    // ---- epilogue: (acc + bias) * active ----
    #pragma unroll
    for (int i = 0; i < 4; ++i) {
        const int m0 = mhalf * 64 + (i << 4) + (q << 2);
        const f32x4 bv = *(const f32x4*)(bias + m0);
        #pragma unroll
        for (int j = 0; j < 8; ++j) {
            const int w = (j << 4) + l16;
            const float a = act[(g << 7) + w];
            float* base = out + (((b << 7) + m0) << 14) + ((h0 + g) << 7) + w;
            #pragma unroll
            for (int rg = 0; rg < 4; ++rg)
                base[rg << 14] = (acc[i][j][rg] + bv[rg]) * a;
        }
    }
}

// ---------------- Round-1 fallback (used only if ws too small) ----------------
#define LDAF 40
__global__ __launch_bounds__(256, 2)
void myconv_fb(const float* __restrict__ x,
               const int* __restrict__ mask,
               const float* __restrict__ wgt,
               const float* __restrict__ bias,
               float* __restrict__ out)
{
    __shared__ unsigned short As[128 * LDAF];
    __shared__ unsigned short Bs[128 * LDAF];
    __shared__ float act[128];

    const int t   = threadIdx.x;
    const int blk = blockIdx.x;
    const int b   = blk >> 7;
    const int h   = blk & 127;

    if (t < 128) {
        int any = 0;
        #pragma unroll
        for (int kh = 0; kh < 3; ++kh) {
            int hh = h + kh - 1;
            if ((unsigned)hh < 128u) {
                const int* mrow = mask + (b * 128 + hh) * 128;
                #pragma unroll
                for (int kw = 0; kw < 3; ++kw) {
                    int ww = t + kw - 1;
                    if ((unsigned)ww < 128u) any |= mrow[ww];
                }
            }
        }
        act[t] = any ? 1.0f : 0.0f;
    }

    const int lane = t & 63;
    const int l16  = lane & 15;
    const int half = lane >> 4;
    const int wv   = t >> 6;
    const int wm   = (wv >> 1) << 6;
    const int wn   = (wv & 1) << 6;

    f32x4 acc[4][4];
    const f32x4 fzero = {0.f, 0.f, 0.f, 0.f};
    #pragma unroll
    for (int i = 0; i < 4; ++i)
        #pragma unroll
        for (int j = 0; j < 4; ++j)
            acc[i][j] = fzero;

    const int am  = t >> 3;
    const int ac4 = (t & 7) << 2;
    const int n     = t & 127;
    const int khalf = __builtin_amdgcn_readfirstlane(t >> 7);
    const int xb    = b << 21;

    for (int kt = 0; kt < 36; ++kt) {
        __syncthreads();
        #pragma unroll
        for (int jj = 0; jj < 4; ++jj) {
            const int m = am + (jj << 5);
            const float4 v = *(const float4*)(wgt + m * 1152 + kt * 32 + ac4);
            unsigned short* dst = &As[m * LDAF + ac4];
            dst[0] = f2bf(v.x); dst[1] = f2bf(v.y); dst[2] = f2bf(v.z); dst[3] = f2bf(v.w);
        }
        u16x8 bv0, bv1;
        #pragma unroll
        for (int s = 0; s < 16; ++s) {
            const int k  = kt * 32 + khalf * 16 + s;
            const int ci = (k * 7282) >> 16;
            const int r  = k - ci * 9;
            const int kh = (r >= 3) + (r >= 6);
            const int kw = r - kh * 3;
            const int hh = h + kh - 1;
            float v = 0.f;
            if ((unsigned)hh < 128u) {
                const int ww = n + kw - 1;
                if ((unsigned)ww < 128u)
                    v = x[xb + (ci << 14) + (hh << 7) + ww];
            }
            if (s < 8) bv0[s] = f2bf(v); else bv1[s - 8] = f2bf(v);
        }
        *(u16x8*)&Bs[n * LDAF + khalf * 16]     = bv0;
        *(u16x8*)&Bs[n * LDAF + khalf * 16 + 8] = bv1;

        __syncthreads();

        bf16x8 af[4], bfr[4];
        #pragma unroll
        for (int i = 0; i < 4; ++i)
            af[i] = *(const bf16x8*)&As[(wm + (i << 4) + l16) * LDAF + (half << 3)];
        #pragma unroll
        for (int j = 0; j < 4; ++j)
            bfr[j] = *(const bf16x8*)&Bs[(wn + (j << 4) + l16) * LDAF + (half << 3)];
        #pragma unroll
        for (int i = 0; i < 4; ++i)
            #pragma unroll
            for (int j = 0; j < 4; ++j)
                acc[i][j] = __builtin_amdgcn_mfma_f32_16x16x32_bf16(af[i], bfr[j], acc[i][j], 0, 0, 0);
    }

    #pragma unroll
    for (int i = 0; i < 4; ++i) {
        #pragma unroll
        for (int j = 0; j < 4; ++j) {
            const int ncol = wn + (j << 4) + l16;
            const float a  = act[ncol];
            #pragma unroll
            for (int rg = 0; rg < 4; ++rg) {
                const int m = wm + (i << 4) + (half << 2) + rg;
                out[(((b << 7) + m) << 14) + (h << 7) + ncol] =
                    (acc[i][j][rg] + bias[m]) * a;
            }
        }
    }
}

extern "C" void kernel_launch(void* const* d_in, const int* in_sizes, int n_in,
                              void* d_out, int out_size, void* d_ws, size_t ws_size,
                              hipStream_t stream) {
    const float* x    = (const float*)d_in[0];
    const int*   mask = (const int*)d_in[1];
    const float* wgt  = (const float*)d_in[2];
    const float* bias = (const float*)d_in[3];
    float* out        = (float*)d_out;

    const size_t XP_ELEMS = 4160ull * 4160;   // 17,305,600 bf16 (8*4*130 slabs)
    const size_t WP_ELEMS = 36ull * 128 * 32; //    147,456 bf16
    const size_t need = (XP_ELEMS + WP_ELEMS) * 2;

    if (ws_size >= need) {
        unsigned short* xpw = (unsigned short*)d_ws;
        unsigned short* wpw = xpw + XP_ELEMS;
        setup_all<<<dim3(4736), dim3(256), 0, stream>>>(x, wgt, xpw, wpw);
        myconv5<<<dim3(1024), dim3(128), 0, stream>>>(xpw, mask, wpw, bias, out);
    } else {
        myconv_fb<<<dim3(1024), dim3(256), 0, stream>>>(x, mask, wgt, bias, out);
    }
}